// Round 17
// baseline (64.522 us; speedup 1.0000x reference)
//
#include <hip/hip_runtime.h>
#include <hip/hip_fp16.h>
#include <cstddef>

// Deformable conv: x(8,128,128,64) f32, offsets(8,128,128,18) f32, W(64,9,128) f32
// out(8,128,128,128) f32.
//
// Round 17: TLP push via finer grid. 4096 blocks x 32 px (was 2048 x 64).
//   R16 lesson: all scheduling knobs null; pipes <26%, occupancy 30%, 8
//   blocks/CU total work -> latency-bound from wave starvation. Halving the
//   block doubles independent barrier groups, drops LDS 22.5->11.3KB and
//   kills the second per-thread Gather (G1) -> ~17 fewer VGPRs.
//   Kept verbatim: XOR-swizzled sampled tile, LDS param tables, fragment-
//   ordered B, distance-2 gather pipeline, lds_barrier, image-per-XCD swizzle.
//   prepass A: x -> f16 xh; prepass B: W -> fragment-ordered f16 wt2.

typedef __attribute__((ext_vector_type(8))) _Float16 f16x8;
typedef __attribute__((ext_vector_type(4))) float    f32x4;

struct __align__(16) H2x4 { __half2 a, b, c, d; };

// ---------------- prepass kernels ----------------

__global__ void cvt_x_kernel(const float* __restrict__ x, __half* __restrict__ xh) {
    int i = blockIdx.x * 256 + threadIdx.x;        // 1,048,576 threads * 8 elems
    const float4* p = (const float4*)x + (size_t)i * 2;
    float4 a = p[0], b = p[1];
    H2x4 o;
    o.a = __floats2half2_rn(a.x, a.y);
    o.b = __floats2half2_rn(a.z, a.w);
    o.c = __floats2half2_rn(b.x, b.y);
    o.d = __floats2half2_rn(b.z, b.w);
    ((H2x4*)xh)[i] = o;
}

// Fragment-ordered W: wt2[(((n*4 + wv)*4 + (nf*2+kf))*64 + ln)*8 + e]
//   = W[c][n][f],  c = kf*32 + (ln>>4)*8 + e,  f = wv*32 + nf*16 + (ln&15).
__global__ void cvt_w_kernel(const float* __restrict__ W, __half* __restrict__ wt2) {
    int idx = blockIdx.x * 256 + threadIdx.x;      // 73728 = 9*4*4*64*8
    if (idx >= 9 * 4 * 4 * 64 * 8) return;
    int e  = idx & 7;
    int ln = (idx >> 3) & 63;
    int fr = (idx >> 9) & 3;
    int wv = (idx >> 11) & 3;
    int n  = idx >> 13;
    int nf = fr >> 1, kf = fr & 1;
    int r = ln & 15, g = ln >> 4;
    int c = kf * 32 + g * 8 + e;
    int f = wv * 32 + nf * 16 + r;
    wt2[idx] = __float2half_rn(W[((size_t)c * 9 + n) * 128 + f]);
}

// ---------------- main MFMA kernel ----------------

// sampled tile: [32 px][64 ch] f16, 128 B/row, XOR-swizzled 16B slots:
//   byte(px, slot) = px*128 + ((slot*16) ^ ((px&7)<<4))
// (write: task(px,c8) -> slot c8; read: ch-octet s at slot s^(px&7)).
// Same swizzle verified 0-conflict/correct since R8.

struct Gather {
    H2x4 v00, v01, v10, v11;
    __half2 wA, wB;      // {w00,w01}, {w10,w11}
};

__device__ inline void issue_gather(const char* __restrict__ ximg,
                                    const unsigned short* __restrict__ pb,
                                    const __half2 (*__restrict__ pw)[2],
                                    int px, int c8, Gather& G)
{
    int base = pb[px];
    G.wA = pw[px][0];
    G.wB = pw[px][1];
    int i0 = base >> 7, j0 = base & 127;
    size_t b00 = ((size_t)base << 7) + (c8 << 4);   // bytes; 128 B per pixel
    int di = (i0 < 127) ? (128 * 128) : 0;
    int dj = (j0 < 127) ? 128 : 0;
    G.v00 = *(const H2x4*)(ximg + b00);
    G.v01 = *(const H2x4*)(ximg + b00 + dj);
    G.v10 = *(const H2x4*)(ximg + b00 + di);
    G.v11 = *(const H2x4*)(ximg + b00 + di + dj);
}

__device__ inline void blend_store(char* __restrict__ buf, unsigned byteoff, const Gather& G)
{
    __half2 w00 = __low2half2(G.wA), w01 = __high2half2(G.wA);
    __half2 w10 = __low2half2(G.wB), w11 = __high2half2(G.wB);
    H2x4 r;
    r.a = __hfma2(G.v11.a, w11, __hfma2(G.v10.a, w10, __hfma2(G.v01.a, w01, __hmul2(G.v00.a, w00))));
    r.b = __hfma2(G.v11.b, w11, __hfma2(G.v10.b, w10, __hfma2(G.v01.b, w01, __hmul2(G.v00.b, w00))));
    r.c = __hfma2(G.v11.c, w11, __hfma2(G.v10.c, w10, __hfma2(G.v01.c, w01, __hmul2(G.v00.c, w00))));
    r.d = __hfma2(G.v11.d, w11, __hfma2(G.v10.d, w10, __hfma2(G.v01.d, w01, __hmul2(G.v00.d, w00))));
    *(H2x4*)(buf + byteoff) = r;
}

// barrier that does NOT drain vmcnt: LDS-write visibility only (R16-verified).
__device__ inline void lds_barrier() {
    __builtin_amdgcn_sched_barrier(0);
    asm volatile("s_waitcnt lgkmcnt(0)" ::: "memory");
    __builtin_amdgcn_s_barrier();
    __builtin_amdgcn_sched_barrier(0);
}

__global__ __launch_bounds__(256, 4)
void defconv_mfma(const float* __restrict__ offs,
                  const __half* __restrict__ xh,
                  const __half* __restrict__ wt,
                  float* __restrict__ out)
{
    __shared__ char sbuf[2][32 * 128];             // 8 KB, double-buffered
    __shared__ unsigned short p_base[9][32];       // (i0<<7)|j0
    __shared__ __half2 p_w[9][32][2];              // bilinear corner weights

    const int t = threadIdx.x;

    // XCD swizzle: dispatch i -> XCD i%8 (heuristic); give XCD k image k.
    int bid = blockIdx.x;
    int wid = (bid & 7) * 512 + (bid >> 3);        // bijective, 4096 % 8 == 0
    const int m   = wid >> 9;                      // image == XCD
    const int h   = (wid >> 2) & 127;              // row
    const int q   = wid & 3;                       // px quarter
    const int pxg = q * 32;

    // ---- phase 0: bilinear params per (px, tap) -> LDS (read offsets ONCE) ----
    const float* offrow = offs + ((size_t)((m * 128 + h) * 128 + pxg)) * 18;
    for (int i = t; i < 288; i += 256) {
        int px = i & 31, n = i >> 5;
        float o0 = offrow[px * 18 + 2 * n];
        float o1 = offrow[px * 18 + 2 * n + 1];
        float ci = fminf(fmaxf((float)h + o0, 0.f), 127.f);
        float cj = fminf(fmaxf((float)(pxg + px) + o1, 0.f), 127.f);
        int i0 = (int)ci;   // floor, ci >= 0
        int j0 = (int)cj;
        float fi = ci - (float)i0, fj = cj - (float)j0;
        float gi = 1.f - fi,       gj = 1.f - fj;
        p_base[n][px] = (unsigned short)((i0 << 7) | j0);
        p_w[n][px][0] = __floats2half2_rn(gi * gj, gi * fj);
        p_w[n][px][1] = __floats2half2_rn(fi * gj, fi * fj);
    }

    const char* ximg = (const char*)(xh + (size_t)m * (128 * 128 * 64));
    const int ln = t & 63;
    const int wv = t >> 6;
    const int r  = ln & 15;
    const int g  = ln >> 4;
    const int n0 = wv * 32;                        // wave's filter strip
    const unsigned rmask = (unsigned)((r & 7) << 4);

    // one task per thread: px0 = t>>3 (0..31), c8 = t&7
    const int px0 = t >> 3;
    const int c8  = t & 7;
    const unsigned off0 = (unsigned)(px0 * 128 + ((c8 * 16) ^ ((px0 & 7) << 4)));

    f32x4 acc[2][2] = {};

    __syncthreads();   // params ready (full drain, once)

    Gather G0;

    // ---- prologue: stage tap 0 fully; prefetch tap 1 into regs ----
    issue_gather(ximg, p_base[0], p_w[0], px0, c8, G0);
    blend_store(sbuf[0], off0, G0);
    issue_gather(ximg, p_base[1], p_w[1], px0, c8, G0);
    lds_barrier();

#pragma unroll 2
    for (int n = 0; n < 9; ++n) {
        char* cur = sbuf[n & 1];
        char* nxt = sbuf[(n + 1) & 1];

        // B fragments for tap n — fragment-ordered, fully coalesced 1KB/instr
        f16x8 bfrag[2][2];
        const __half* wb = wt + (size_t)(n * 4 + wv) * (4 * 512);
#pragma unroll
        for (int nf = 0; nf < 2; ++nf)
#pragma unroll
            for (int kf = 0; kf < 2; ++kf)
                bfrag[nf][kf] = *(const f16x8*)(wb + ((nf * 2 + kf) * 64 + ln) * 8);

        // blend tap n+1 (loads issued a FULL iteration ago), refill with tap n+2
        if (n < 8) blend_store(nxt, off0, G0);
        if (n < 7) issue_gather(ximg, p_base[n + 2], p_w[n + 2], px0, c8, G0);

        __builtin_amdgcn_s_setprio(1);
#pragma unroll
        for (int mf = 0; mf < 2; ++mf) {
            int row = mf * 16 + r;
            unsigned o0 = (unsigned)(row * 128) + ((unsigned)(g * 16)      ^ rmask);
            unsigned o1 = (unsigned)(row * 128) + ((unsigned)(g * 16 + 64) ^ rmask);
            f16x8 a0 = *(const f16x8*)(cur + o0);
            f16x8 a1 = *(const f16x8*)(cur + o1);
            acc[mf][0] = __builtin_amdgcn_mfma_f32_16x16x32_f16(a0, bfrag[0][0], acc[mf][0], 0, 0, 0);
            acc[mf][1] = __builtin_amdgcn_mfma_f32_16x16x32_f16(a0, bfrag[1][0], acc[mf][1], 0, 0, 0);
            acc[mf][0] = __builtin_amdgcn_mfma_f32_16x16x32_f16(a1, bfrag[0][1], acc[mf][0], 0, 0, 0);
            acc[mf][1] = __builtin_amdgcn_mfma_f32_16x16x32_f16(a1, bfrag[1][1], acc[mf][1], 0, 0, 0);
        }
        __builtin_amdgcn_s_setprio(0);

        // LDS-visibility barrier ONLY: in-flight gathers ride across.
        lds_barrier();
    }

    // ---- epilogue: D[px][f], col = lane&15 -> f, row = (lane>>4)*4 + reg -> px ----
    float* orow = out + ((size_t)((m * 128 + h) * 128 + pxg)) * 128;
#pragma unroll
    for (int mf = 0; mf < 2; ++mf)
#pragma unroll
        for (int nf = 0; nf < 2; ++nf) {
            int f    = n0 + nf * 16 + r;
            int px0e = mf * 16 + g * 4;
#pragma unroll
            for (int qq = 0; qq < 4; ++qq)
                orow[(size_t)(px0e + qq) * 128 + f] = acc[mf][nf][qq];
        }
}

// ---------------- fp32 fallback (if ws too small) ----------------

constexpr int Hh   = 128;
constexpr int Wdim = 128;
constexpr int Cc   = 64;
constexpr int NTAP = 9;
constexpr int Ff   = 128;
constexpr int PXB  = 128;
constexpr int SPAD = 132;

__global__ __launch_bounds__(256, 2)
void defconv_f32(const float* __restrict__ x,
                 const float* __restrict__ offs,
                 const float* __restrict__ Wt,
                 float* __restrict__ out)
{
    __shared__ float s_tile[Cc][SPAD];
    __shared__ float w_tile[Cc][Ff];
    __shared__ float off_lds[PXB * 2 * NTAP];

    const int t   = threadIdx.x;
    const int bid = blockIdx.x;
    const int m   = bid >> 7;
    const int h   = bid & 127;

    const float* offrow = offs + (size_t)(m * Hh + h) * Wdim * (2 * NTAP);
    for (int i = t; i < PXB * 2 * NTAP; i += 256) off_lds[i] = offrow[i];

    const int pg = t & 15;
    const int fg = t >> 4;
    const int p0 = pg * 8;
    const int f0 = fg * 8;

    float acc[8][8];
#pragma unroll
    for (int a = 0; a < 8; ++a)
#pragma unroll
        for (int b = 0; b < 8; ++b) acc[a][b] = 0.f;

    const float* xbase = x + (size_t)m * Hh * Wdim * Cc;
    __syncthreads();

    for (int n = 0; n < NTAP; ++n) {
#pragma unroll
        for (int i = 0; i < 8; ++i) {
            int idx = t + 256 * i;
            int c   = idx >> 5;
            int f4  = (idx & 31) * 4;
            *(float4*)&w_tile[c][f4] =
                *(const float4*)(Wt + ((size_t)c * NTAP + n) * Ff + f4);
        }
#pragma unroll
        for (int i = 0; i < 8; ++i) {
            int task = t + 256 * i;
            int px   = task >> 4;
            int c4   = (task & 15) * 4;
            float o0 = off_lds[px * (2 * NTAP) + 2 * n];
            float o1 = off_lds[px * (2 * NTAP) + 2 * n + 1];
            float ci = fminf(fmaxf((float)h  + o0, 0.f), 127.f);
            float cj = fminf(fmaxf((float)px + o1, 0.f), 127.f);
            int i0 = (int)floorf(ci);
            int i1 = (int)ceilf(ci);
            int j0 = (int)floorf(cj);
            int j1 = (int)ceilf(cj);
            float fi = ci - (float)i0;
            float fj = cj - (float)j0;
            const float* r00 = xbase + ((size_t)i0 * Wdim + j0) * Cc + c4;
            const float* r01 = xbase + ((size_t)i0 * Wdim + j1) * Cc + c4;
            const float* r10 = xbase + ((size_t)i1 * Wdim + j0) * Cc + c4;
            const float* r11 = xbase + ((size_t)i1 * Wdim + j1) * Cc + c4;
            float4 vlt = *(const float4*)r00;
            float4 vrt = *(const float4*)r01;
            float4 vlb = *(const float4*)r10;
            float4 vrb = *(const float4*)r11;
            {
                float vt = vlt.x + (vrt.x - vlt.x) * fj;
                float vb = vlb.x + (vrb.x - vlb.x) * fj;
                s_tile[c4 + 0][px] = vt + (vb - vt) * fi;
            }
            {
                float vt = vlt.y + (vrt.y - vlt.y) * fj;
                float vb = vlb.y + (vrb.y - vlb.y) * fj;
                s_tile[c4 + 1][px] = vt + (vb - vt) * fi;
            }
            {
                float vt = vlt.z + (vrt.z - vlt.z) * fj;
                float vb = vlb.z + (vrb.z - vlb.z) * fj;
                s_tile[c4 + 2][px] = vt + (vb - vt) * fi;
            }
            {
                float vt = vlt.w + (vrt.w - vlt.w) * fj;
                float vb = vlb.w + (vrb.w - vlb.w) * fj;
                s_tile[c4 + 3][px] = vt + (vb - vt) * fi;
            }
        }
        __syncthreads();
        for (int c = 0; c < Cc; ++c) {
            float a[8], b[8];
            *(float4*)&a[0] = *(const float4*)&s_tile[c][p0];
            *(float4*)&a[4] = *(const float4*)&s_tile[c][p0 + 4];
            *(float4*)&b[0] = *(const float4*)&w_tile[c][f0];
            *(float4*)&b[4] = *(const float4*)&w_tile[c][f0 + 4];
#pragma unroll
            for (int pp = 0; pp < 8; ++pp)
#pragma unroll
                for (int ff = 0; ff < 8; ++ff)
                    acc[pp][ff] = fmaf(a[pp], b[ff], acc[pp][ff]);
        }
        __syncthreads();
    }

    float* orow = out + (size_t)(m * Hh + h) * Wdim * Ff;
#pragma unroll
    for (int pp = 0; pp < 8; ++pp) {
        float4 v0 = make_float4(acc[pp][0], acc[pp][1], acc[pp][2], acc[pp][3]);
        float4 v1 = make_float4(acc[pp][4], acc[pp][5], acc[pp][6], acc[pp][7]);
        *(float4*)&orow[(size_t)(p0 + pp) * Ff + f0]     = v0;
        *(float4*)&orow[(size_t)(p0 + pp) * Ff + f0 + 4] = v1;
    }
}

// ---------------- launch ----------------

extern "C" void kernel_launch(void* const* d_in, const int* in_sizes, int n_in,
                              void* d_out, int out_size, void* d_ws, size_t ws_size,
                              hipStream_t stream) {
    const float* x    = (const float*)d_in[0];
    const float* offs = (const float*)d_in[1];
    const float* W    = (const float*)d_in[2];
    float* out        = (float*)d_out;

    const size_t XH_BYTES = (size_t)8 * 128 * 128 * 64 * 2;   // 16,777,216
    const size_t WT_BYTES = (size_t)9 * 4 * 4 * 64 * 8 * 2;   // 147,456

    if (ws_size >= XH_BYTES + WT_BYTES) {
        __half* xh = (__half*)d_ws;
        __half* wt = (__half*)((char*)d_ws + XH_BYTES);
        cvt_w_kernel<<<dim3(288),  dim3(256), 0, stream>>>(W, wt);
        cvt_x_kernel<<<dim3(4096), dim3(256), 0, stream>>>(x, xh);
        defconv_mfma<<<dim3(4096), dim3(256), 0, stream>>>(offs, xh, wt, out);
    } else {
        defconv_f32<<<dim3(1024), dim3(256), 0, stream>>>(x, offs, W, out);
    }
}

// Round 18
// 64.459 us; speedup vs baseline: 1.0010x; 1.0010x over previous
//
#include <hip/hip_runtime.h>
#include <hip/hip_fp16.h>
#include <cstddef>

// Deformable conv: x(8,128,128,64) f32, offsets(8,128,128,18) f32, W(64,9,128) f32
// out(8,128,128,128) f32.
//
// Round 17: TLP push via finer grid. 4096 blocks x 32 px (was 2048 x 64).
//   R16 lesson: all scheduling knobs null; pipes <26%, occupancy 30%, 8
//   blocks/CU total work -> latency-bound from wave starvation. Halving the
//   block doubles independent barrier groups, drops LDS 22.5->11.3KB and
//   kills the second per-thread Gather (G1) -> ~17 fewer VGPRs.
//   Kept verbatim: XOR-swizzled sampled tile, LDS param tables, fragment-
//   ordered B, distance-2 gather pipeline, lds_barrier, image-per-XCD swizzle.
//   prepass A: x -> f16 xh; prepass B: W -> fragment-ordered f16 wt2.

typedef __attribute__((ext_vector_type(8))) _Float16 f16x8;
typedef __attribute__((ext_vector_type(4))) float    f32x4;

struct __align__(16) H2x4 { __half2 a, b, c, d; };

// ---------------- prepass kernels ----------------

__global__ void cvt_x_kernel(const float* __restrict__ x, __half* __restrict__ xh) {
    int i = blockIdx.x * 256 + threadIdx.x;        // 1,048,576 threads * 8 elems
    const float4* p = (const float4*)x + (size_t)i * 2;
    float4 a = p[0], b = p[1];
    H2x4 o;
    o.a = __floats2half2_rn(a.x, a.y);
    o.b = __floats2half2_rn(a.z, a.w);
    o.c = __floats2half2_rn(b.x, b.y);
    o.d = __floats2half2_rn(b.z, b.w);
    ((H2x4*)xh)[i] = o;
}

// Fragment-ordered W: wt2[(((n*4 + wv)*4 + (nf*2+kf))*64 + ln)*8 + e]
//   = W[c][n][f],  c = kf*32 + (ln>>4)*8 + e,  f = wv*32 + nf*16 + (ln&15).
__global__ void cvt_w_kernel(const float* __restrict__ W, __half* __restrict__ wt2) {
    int idx = blockIdx.x * 256 + threadIdx.x;      // 73728 = 9*4*4*64*8
    if (idx >= 9 * 4 * 4 * 64 * 8) return;
    int e  = idx & 7;
    int ln = (idx >> 3) & 63;
    int fr = (idx >> 9) & 3;
    int wv = (idx >> 11) & 3;
    int n  = idx >> 13;
    int nf = fr >> 1, kf = fr & 1;
    int r = ln & 15, g = ln >> 4;
    int c = kf * 32 + g * 8 + e;
    int f = wv * 32 + nf * 16 + r;
    wt2[idx] = __float2half_rn(W[((size_t)c * 9 + n) * 128 + f]);
}

// ---------------- main MFMA kernel ----------------

// sampled tile: [32 px][64 ch] f16, 128 B/row, XOR-swizzled 16B slots:
//   byte(px, slot) = px*128 + ((slot*16) ^ ((px&7)<<4))
// (write: task(px,c8) -> slot c8; read: ch-octet s at slot s^(px&7)).
// Same swizzle verified 0-conflict/correct since R8.

struct Gather {
    H2x4 v00, v01, v10, v11;
    __half2 wA, wB;      // {w00,w01}, {w10,w11}
};

__device__ inline void issue_gather(const char* __restrict__ ximg,
                                    const unsigned short* __restrict__ pb,
                                    const __half2 (*__restrict__ pw)[2],
                                    int px, int c8, Gather& G)
{
    int base = pb[px];
    G.wA = pw[px][0];
    G.wB = pw[px][1];
    int i0 = base >> 7, j0 = base & 127;
    size_t b00 = ((size_t)base << 7) + (c8 << 4);   // bytes; 128 B per pixel
    int di = (i0 < 127) ? (128 * 128) : 0;
    int dj = (j0 < 127) ? 128 : 0;
    G.v00 = *(const H2x4*)(ximg + b00);
    G.v01 = *(const H2x4*)(ximg + b00 + dj);
    G.v10 = *(const H2x4*)(ximg + b00 + di);
    G.v11 = *(const H2x4*)(ximg + b00 + di + dj);
}

__device__ inline void blend_store(char* __restrict__ buf, unsigned byteoff, const Gather& G)
{
    __half2 w00 = __low2half2(G.wA), w01 = __high2half2(G.wA);
    __half2 w10 = __low2half2(G.wB), w11 = __high2half2(G.wB);
    H2x4 r;
    r.a = __hfma2(G.v11.a, w11, __hfma2(G.v10.a, w10, __hfma2(G.v01.a, w01, __hmul2(G.v00.a, w00))));
    r.b = __hfma2(G.v11.b, w11, __hfma2(G.v10.b, w10, __hfma2(G.v01.b, w01, __hmul2(G.v00.b, w00))));
    r.c = __hfma2(G.v11.c, w11, __hfma2(G.v10.c, w10, __hfma2(G.v01.c, w01, __hmul2(G.v00.c, w00))));
    r.d = __hfma2(G.v11.d, w11, __hfma2(G.v10.d, w10, __hfma2(G.v01.d, w01, __hmul2(G.v00.d, w00))));
    *(H2x4*)(buf + byteoff) = r;
}

// barrier that does NOT drain vmcnt: LDS-write visibility only (R16-verified).
__device__ inline void lds_barrier() {
    __builtin_amdgcn_sched_barrier(0);
    asm volatile("s_waitcnt lgkmcnt(0)" ::: "memory");
    __builtin_amdgcn_s_barrier();
    __builtin_amdgcn_sched_barrier(0);
}

__global__ __launch_bounds__(256, 4)
void defconv_mfma(const float* __restrict__ offs,
                  const __half* __restrict__ xh,
                  const __half* __restrict__ wt,
                  float* __restrict__ out)
{
    __shared__ char sbuf[2][32 * 128];             // 8 KB, double-buffered
    __shared__ unsigned short p_base[9][32];       // (i0<<7)|j0
    __shared__ __half2 p_w[9][32][2];              // bilinear corner weights

    const int t = threadIdx.x;

    // XCD swizzle: dispatch i -> XCD i%8 (heuristic); give XCD k image k.
    int bid = blockIdx.x;
    int wid = (bid & 7) * 512 + (bid >> 3);        // bijective, 4096 % 8 == 0
    const int m   = wid >> 9;                      // image == XCD
    const int h   = (wid >> 2) & 127;              // row
    const int q   = wid & 3;                       // px quarter
    const int pxg = q * 32;

    // ---- phase 0: bilinear params per (px, tap) -> LDS (read offsets ONCE) ----
    const float* offrow = offs + ((size_t)((m * 128 + h) * 128 + pxg)) * 18;
    for (int i = t; i < 288; i += 256) {
        int px = i & 31, n = i >> 5;
        float o0 = offrow[px * 18 + 2 * n];
        float o1 = offrow[px * 18 + 2 * n + 1];
        float ci = fminf(fmaxf((float)h + o0, 0.f), 127.f);
        float cj = fminf(fmaxf((float)(pxg + px) + o1, 0.f), 127.f);
        int i0 = (int)ci;   // floor, ci >= 0
        int j0 = (int)cj;
        float fi = ci - (float)i0, fj = cj - (float)j0;
        float gi = 1.f - fi,       gj = 1.f - fj;
        p_base[n][px] = (unsigned short)((i0 << 7) | j0);
        p_w[n][px][0] = __floats2half2_rn(gi * gj, gi * fj);
        p_w[n][px][1] = __floats2half2_rn(fi * gj, fi * fj);
    }

    const char* ximg = (const char*)(xh + (size_t)m * (128 * 128 * 64));
    const int ln = t & 63;
    const int wv = t >> 6;
    const int r  = ln & 15;
    const int g  = ln >> 4;
    const int n0 = wv * 32;                        // wave's filter strip
    const unsigned rmask = (unsigned)((r & 7) << 4);

    // one task per thread: px0 = t>>3 (0..31), c8 = t&7
    const int px0 = t >> 3;
    const int c8  = t & 7;
    const unsigned off0 = (unsigned)(px0 * 128 + ((c8 * 16) ^ ((px0 & 7) << 4)));

    f32x4 acc[2][2] = {};

    __syncthreads();   // params ready (full drain, once)

    Gather G0;

    // ---- prologue: stage tap 0 fully; prefetch tap 1 into regs ----
    issue_gather(ximg, p_base[0], p_w[0], px0, c8, G0);
    blend_store(sbuf[0], off0, G0);
    issue_gather(ximg, p_base[1], p_w[1], px0, c8, G0);
    lds_barrier();

#pragma unroll 2
    for (int n = 0; n < 9; ++n) {
        char* cur = sbuf[n & 1];
        char* nxt = sbuf[(n + 1) & 1];

        // B fragments for tap n — fragment-ordered, fully coalesced 1KB/instr
        f16x8 bfrag[2][2];
        const __half* wb = wt + (size_t)(n * 4 + wv) * (4 * 512);
#pragma unroll
        for (int nf = 0; nf < 2; ++nf)
#pragma unroll
            for (int kf = 0; kf < 2; ++kf)
                bfrag[nf][kf] = *(const f16x8*)(wb + ((nf * 2 + kf) * 64 + ln) * 8);

        // blend tap n+1 (loads issued a FULL iteration ago), refill with tap n+2
        if (n < 8) blend_store(nxt, off0, G0);
        if (n < 7) issue_gather(ximg, p_base[n + 2], p_w[n + 2], px0, c8, G0);

        __builtin_amdgcn_s_setprio(1);
#pragma unroll
        for (int mf = 0; mf < 2; ++mf) {
            int row = mf * 16 + r;
            unsigned o0 = (unsigned)(row * 128) + ((unsigned)(g * 16)      ^ rmask);
            unsigned o1 = (unsigned)(row * 128) + ((unsigned)(g * 16 + 64) ^ rmask);
            f16x8 a0 = *(const f16x8*)(cur + o0);
            f16x8 a1 = *(const f16x8*)(cur + o1);
            acc[mf][0] = __builtin_amdgcn_mfma_f32_16x16x32_f16(a0, bfrag[0][0], acc[mf][0], 0, 0, 0);
            acc[mf][1] = __builtin_amdgcn_mfma_f32_16x16x32_f16(a0, bfrag[1][0], acc[mf][1], 0, 0, 0);
            acc[mf][0] = __builtin_amdgcn_mfma_f32_16x16x32_f16(a1, bfrag[0][1], acc[mf][0], 0, 0, 0);
            acc[mf][1] = __builtin_amdgcn_mfma_f32_16x16x32_f16(a1, bfrag[1][1], acc[mf][1], 0, 0, 0);
        }
        __builtin_amdgcn_s_setprio(0);

        // LDS-visibility barrier ONLY: in-flight gathers ride across.
        lds_barrier();
    }

    // ---- epilogue: D[px][f], col = lane&15 -> f, row = (lane>>4)*4 + reg -> px ----
    float* orow = out + ((size_t)((m * 128 + h) * 128 + pxg)) * 128;
#pragma unroll
    for (int mf = 0; mf < 2; ++mf)
#pragma unroll
        for (int nf = 0; nf < 2; ++nf) {
            int f    = n0 + nf * 16 + r;
            int px0e = mf * 16 + g * 4;
#pragma unroll
            for (int qq = 0; qq < 4; ++qq)
                orow[(size_t)(px0e + qq) * 128 + f] = acc[mf][nf][qq];
        }
}

// ---------------- fp32 fallback (if ws too small) ----------------

constexpr int Hh   = 128;
constexpr int Wdim = 128;
constexpr int Cc   = 64;
constexpr int NTAP = 9;
constexpr int Ff   = 128;
constexpr int PXB  = 128;
constexpr int SPAD = 132;

__global__ __launch_bounds__(256, 2)
void defconv_f32(const float* __restrict__ x,
                 const float* __restrict__ offs,
                 const float* __restrict__ Wt,
                 float* __restrict__ out)
{
    __shared__ float s_tile[Cc][SPAD];
    __shared__ float w_tile[Cc][Ff];
    __shared__ float off_lds[PXB * 2 * NTAP];

    const int t   = threadIdx.x;
    const int bid = blockIdx.x;
    const int m   = bid >> 7;
    const int h   = bid & 127;

    const float* offrow = offs + (size_t)(m * Hh + h) * Wdim * (2 * NTAP);
    for (int i = t; i < PXB * 2 * NTAP; i += 256) off_lds[i] = offrow[i];

    const int pg = t & 15;
    const int fg = t >> 4;
    const int p0 = pg * 8;
    const int f0 = fg * 8;

    float acc[8][8];
#pragma unroll
    for (int a = 0; a < 8; ++a)
#pragma unroll
        for (int b = 0; b < 8; ++b) acc[a][b] = 0.f;

    const float* xbase = x + (size_t)m * Hh * Wdim * Cc;
    __syncthreads();

    for (int n = 0; n < NTAP; ++n) {
#pragma unroll
        for (int i = 0; i < 8; ++i) {
            int idx = t + 256 * i;
            int c   = idx >> 5;
            int f4  = (idx & 31) * 4;
            *(float4*)&w_tile[c][f4] =
                *(const float4*)(Wt + ((size_t)c * NTAP + n) * Ff + f4);
        }
#pragma unroll
        for (int i = 0; i < 8; ++i) {
            int task = t + 256 * i;
            int px   = task >> 4;
            int c4   = (task & 15) * 4;
            float o0 = off_lds[px * (2 * NTAP) + 2 * n];
            float o1 = off_lds[px * (2 * NTAP) + 2 * n + 1];
            float ci = fminf(fmaxf((float)h  + o0, 0.f), 127.f);
            float cj = fminf(fmaxf((float)px + o1, 0.f), 127.f);
            int i0 = (int)floorf(ci);
            int i1 = (int)ceilf(ci);
            int j0 = (int)floorf(cj);
            int j1 = (int)ceilf(cj);
            float fi = ci - (float)i0;
            float fj = cj - (float)j0;
            const float* r00 = xbase + ((size_t)i0 * Wdim + j0) * Cc + c4;
            const float* r01 = xbase + ((size_t)i0 * Wdim + j1) * Cc + c4;
            const float* r10 = xbase + ((size_t)i1 * Wdim + j0) * Cc + c4;
            const float* r11 = xbase + ((size_t)i1 * Wdim + j1) * Cc + c4;
            float4 vlt = *(const float4*)r00;
            float4 vrt = *(const float4*)r01;
            float4 vlb = *(const float4*)r10;
            float4 vrb = *(const float4*)r11;
            {
                float vt = vlt.x + (vrt.x - vlt.x) * fj;
                float vb = vlb.x + (vrb.x - vlb.x) * fj;
                s_tile[c4 + 0][px] = vt + (vb - vt) * fi;
            }
            {
                float vt = vlt.y + (vrt.y - vlt.y) * fj;
                float vb = vlb.y + (vrb.y - vlb.y) * fj;
                s_tile[c4 + 1][px] = vt + (vb - vt) * fi;
            }
            {
                float vt = vlt.z + (vrt.z - vlt.z) * fj;
                float vb = vlb.z + (vrb.z - vlb.z) * fj;
                s_tile[c4 + 2][px] = vt + (vb - vt) * fi;
            }
            {
                float vt = vlt.w + (vrt.w - vlt.w) * fj;
                float vb = vlb.w + (vrb.w - vlb.w) * fj;
                s_tile[c4 + 3][px] = vt + (vb - vt) * fi;
            }
        }
        __syncthreads();
        for (int c = 0; c < Cc; ++c) {
            float a[8], b[8];
            *(float4*)&a[0] = *(const float4*)&s_tile[c][p0];
            *(float4*)&a[4] = *(const float4*)&s_tile[c][p0 + 4];
            *(float4*)&b[0] = *(const float4*)&w_tile[c][f0];
            *(float4*)&b[4] = *(const float4*)&w_tile[c][f0 + 4];
#pragma unroll
            for (int pp = 0; pp < 8; ++pp)
#pragma unroll
                for (int ff = 0; ff < 8; ++ff)
                    acc[pp][ff] = fmaf(a[pp], b[ff], acc[pp][ff]);
        }
        __syncthreads();
    }

    float* orow = out + (size_t)(m * Hh + h) * Wdim * Ff;
#pragma unroll
    for (int pp = 0; pp < 8; ++pp) {
        float4 v0 = make_float4(acc[pp][0], acc[pp][1], acc[pp][2], acc[pp][3]);
        float4 v1 = make_float4(acc[pp][4], acc[pp][5], acc[pp][6], acc[pp][7]);
        *(float4*)&orow[(size_t)(p0 + pp) * Ff + f0]     = v0;
        *(float4*)&orow[(size_t)(p0 + pp) * Ff + f0 + 4] = v1;
    }
}

// ---------------- launch ----------------

extern "C" void kernel_launch(void* const* d_in, const int* in_sizes, int n_in,
                              void* d_out, int out_size, void* d_ws, size_t ws_size,
                              hipStream_t stream) {
    const float* x    = (const float*)d_in[0];
    const float* offs = (const float*)d_in[1];
    const float* W    = (const float*)d_in[2];
    float* out        = (float*)d_out;

    const size_t XH_BYTES = (size_t)8 * 128 * 128 * 64 * 2;   // 16,777,216
    const size_t WT_BYTES = (size_t)9 * 4 * 4 * 64 * 8 * 2;   // 147,456

    if (ws_size >= XH_BYTES + WT_BYTES) {
        __half* xh = (__half*)d_ws;
        __half* wt = (__half*)((char*)d_ws + XH_BYTES);
        cvt_w_kernel<<<dim3(288),  dim3(256), 0, stream>>>(W, wt);
        cvt_x_kernel<<<dim3(4096), dim3(256), 0, stream>>>(x, xh);
        defconv_mfma<<<dim3(4096), dim3(256), 0, stream>>>(offs, xh, wt, out);
    } else {
        defconv_f32<<<dim3(1024), dim3(256), 0, stream>>>(x, offs, W, out);
    }
}

// Round 19
// 59.481 us; speedup vs baseline: 1.0847x; 1.0837x over previous
//
#include <hip/hip_runtime.h>
#include <hip/hip_fp16.h>
#include <cstddef>

// Deformable conv: x(8,128,128,64) f32, offsets(8,128,128,18) f32, W(64,9,128) f32
// out(8,128,128,128) f32.
//
// Round 19: 8-wave blocks, same tile. 2048 blocks x 64 px x 512 threads.
//   R17 lesson: halving block by PIXELS duplicates B traffic (each block reads
//   full 16KB B/tap). Halving per-thread work by DOUBLING WAVES keeps all
//   traffic identical (N-split 16 filters/wave divides B) and doubles the
//   waves available for latency hiding. One task/thread -> G1 gone -> ~47
//   live regs, fits the 64-VGPR cap of launch_bounds(512,8) -> 32 waves/CU.
//   Kept verbatim: XOR-swizzled sampled tile, LDS param tables, fragment-
//   ordered B, distance-2 gather pipeline, lds_barrier, image-per-XCD swizzle.
//   prepass A: x -> f16 xh; prepass B: W -> 8-wave fragment order wt8.

typedef __attribute__((ext_vector_type(8))) _Float16 f16x8;
typedef __attribute__((ext_vector_type(4))) float    f32x4;

struct __align__(16) H2x4 { __half2 a, b, c, d; };

// ---------------- prepass kernels ----------------

__global__ void cvt_x_kernel(const float* __restrict__ x, __half* __restrict__ xh) {
    int i = blockIdx.x * 256 + threadIdx.x;        // 1,048,576 threads * 8 elems
    const float4* p = (const float4*)x + (size_t)i * 2;
    float4 a = p[0], b = p[1];
    H2x4 o;
    o.a = __floats2half2_rn(a.x, a.y);
    o.b = __floats2half2_rn(a.z, a.w);
    o.c = __floats2half2_rn(b.x, b.y);
    o.d = __floats2half2_rn(b.z, b.w);
    ((H2x4*)xh)[i] = o;
}

// 8-wave fragment-ordered W: wt8[(((n*8 + wv)*2 + kf)*64 + ln)*8 + e]
//   = W[c][n][f],  c = kf*32 + (ln>>4)*8 + e,  f = wv*16 + (ln&15).
__global__ void cvt_w_kernel(const float* __restrict__ W, __half* __restrict__ wt8) {
    int idx = blockIdx.x * 256 + threadIdx.x;      // 73728 = 9*8*2*64*8
    if (idx >= 9 * 8 * 2 * 64 * 8) return;
    int e  = idx & 7;
    int ln = (idx >> 3) & 63;
    int kf = (idx >> 9) & 1;
    int wv = (idx >> 10) & 7;
    int n  = idx >> 13;
    int c = kf * 32 + (ln >> 4) * 8 + e;
    int f = wv * 16 + (ln & 15);
    wt8[idx] = __float2half_rn(W[((size_t)c * 9 + n) * 128 + f]);
}

// ---------------- main MFMA kernel ----------------

// sampled tile: [64 px][64 ch] f16, 128 B/row, XOR-swizzled 16B slots:
//   byte(px, slot) = px*128 + ((slot*16) ^ ((px&7)<<4))
// (write: task(px,c8) -> slot c8; read: ch-octet s at slot s^(px&7)).
// Same swizzle verified 0-conflict/correct since R8.

struct Gather {
    H2x4 v00, v01, v10, v11;
    __half2 wA, wB;      // {w00,w01}, {w10,w11}
};

__device__ inline void issue_gather(const char* __restrict__ ximg,
                                    const unsigned short* __restrict__ pb,
                                    const __half2 (*__restrict__ pw)[2],
                                    int px, int c8, Gather& G)
{
    int base = pb[px];
    G.wA = pw[px][0];
    G.wB = pw[px][1];
    int i0 = base >> 7, j0 = base & 127;
    size_t b00 = ((size_t)base << 7) + (c8 << 4);   // bytes; 128 B per pixel
    int di = (i0 < 127) ? (128 * 128) : 0;
    int dj = (j0 < 127) ? 128 : 0;
    G.v00 = *(const H2x4*)(ximg + b00);
    G.v01 = *(const H2x4*)(ximg + b00 + dj);
    G.v10 = *(const H2x4*)(ximg + b00 + di);
    G.v11 = *(const H2x4*)(ximg + b00 + di + dj);
}

__device__ inline void blend_store(char* __restrict__ buf, unsigned byteoff, const Gather& G)
{
    __half2 w00 = __low2half2(G.wA), w01 = __high2half2(G.wA);
    __half2 w10 = __low2half2(G.wB), w11 = __high2half2(G.wB);
    H2x4 r;
    r.a = __hfma2(G.v11.a, w11, __hfma2(G.v10.a, w10, __hfma2(G.v01.a, w01, __hmul2(G.v00.a, w00))));
    r.b = __hfma2(G.v11.b, w11, __hfma2(G.v10.b, w10, __hfma2(G.v01.b, w01, __hmul2(G.v00.b, w00))));
    r.c = __hfma2(G.v11.c, w11, __hfma2(G.v10.c, w10, __hfma2(G.v01.c, w01, __hmul2(G.v00.c, w00))));
    r.d = __hfma2(G.v11.d, w11, __hfma2(G.v10.d, w10, __hfma2(G.v01.d, w01, __hmul2(G.v00.d, w00))));
    *(H2x4*)(buf + byteoff) = r;
}

// barrier that does NOT drain vmcnt: LDS-write visibility only (R16-verified).
__device__ inline void lds_barrier() {
    __builtin_amdgcn_sched_barrier(0);
    asm volatile("s_waitcnt lgkmcnt(0)" ::: "memory");
    __builtin_amdgcn_s_barrier();
    __builtin_amdgcn_sched_barrier(0);
}

__global__ __launch_bounds__(512, 8)
void defconv_mfma(const float* __restrict__ offs,
                  const __half* __restrict__ xh,
                  const __half* __restrict__ wt,
                  float* __restrict__ out)
{
    __shared__ char sbuf[2][64 * 128];             // 16 KB, double-buffered
    __shared__ unsigned short p_base[9][64];       // (i0<<7)|j0
    __shared__ __half2 p_w[9][64][2];              // bilinear corner weights

    const int t = threadIdx.x;

    // XCD swizzle: dispatch i -> XCD i%8 (heuristic); give XCD k image k.
    int bid = blockIdx.x;
    int wid = (bid & 7) * 256 + (bid >> 3);        // bijective, 2048 % 8 == 0
    const int m   = wid >> 8;                      // image == XCD
    const int h   = (wid >> 1) & 127;              // row
    const int q   = wid & 1;                       // px half
    const int pxg = q * 64;

    // ---- phase 0: bilinear params per (px, tap) -> LDS (read offsets ONCE) ----
    const float* offrow = offs + ((size_t)((m * 128 + h) * 128 + pxg)) * 18;
    for (int i = t; i < 576; i += 512) {
        int px = i & 63, n = i >> 6;
        float o0 = offrow[px * 18 + 2 * n];
        float o1 = offrow[px * 18 + 2 * n + 1];
        float ci = fminf(fmaxf((float)h + o0, 0.f), 127.f);
        float cj = fminf(fmaxf((float)(pxg + px) + o1, 0.f), 127.f);
        int i0 = (int)ci;   // floor, ci >= 0
        int j0 = (int)cj;
        float fi = ci - (float)i0, fj = cj - (float)j0;
        float gi = 1.f - fi,       gj = 1.f - fj;
        p_base[n][px] = (unsigned short)((i0 << 7) | j0);
        p_w[n][px][0] = __floats2half2_rn(gi * gj, gi * fj);
        p_w[n][px][1] = __floats2half2_rn(fi * gj, fi * fj);
    }

    const char* ximg = (const char*)(xh + (size_t)m * (128 * 128 * 64));
    const int ln = t & 63;
    const int wv = t >> 6;                         // 0..7
    const int r  = ln & 15;
    const int g  = ln >> 4;
    const int n0 = wv * 16;                        // wave's 16-filter strip
    const unsigned rmask = (unsigned)((r & 7) << 4);

    // one task per thread: px0 = t>>3 (0..63), c8 = t&7
    const int px0 = t >> 3;
    const int c8  = t & 7;
    const unsigned off0 = (unsigned)(px0 * 128 + ((c8 * 16) ^ ((px0 & 7) << 4)));

    f32x4 acc[4] = {};

    __syncthreads();   // params ready (full drain, once)

    Gather G0;

    // ---- prologue: stage tap 0 fully; prefetch tap 1 into regs ----
    issue_gather(ximg, p_base[0], p_w[0], px0, c8, G0);
    blend_store(sbuf[0], off0, G0);
    issue_gather(ximg, p_base[1], p_w[1], px0, c8, G0);
    lds_barrier();

#pragma unroll 2
    for (int n = 0; n < 9; ++n) {
        char* cur = sbuf[n & 1];
        char* nxt = sbuf[(n + 1) & 1];

        // B fragments for tap n — 8-wave fragment order, 2 x 1KB contiguous
        f16x8 bfrag[2];
        const __half* wb = wt + (size_t)(n * 8 + wv) * 1024;
#pragma unroll
        for (int kf = 0; kf < 2; ++kf)
            bfrag[kf] = *(const f16x8*)(wb + (kf * 64 + ln) * 8);

        // blend tap n+1 (loads issued a FULL iteration ago), refill with tap n+2
        if (n < 8) blend_store(nxt, off0, G0);
        if (n < 7) issue_gather(ximg, p_base[n + 2], p_w[n + 2], px0, c8, G0);

        __builtin_amdgcn_s_setprio(1);
#pragma unroll
        for (int mf = 0; mf < 4; ++mf) {
            int row = mf * 16 + r;
            unsigned o0 = (unsigned)(row * 128) + ((unsigned)(g * 16)      ^ rmask);
            unsigned o1 = (unsigned)(row * 128) + ((unsigned)(g * 16 + 64) ^ rmask);
            f16x8 a0 = *(const f16x8*)(cur + o0);
            f16x8 a1 = *(const f16x8*)(cur + o1);
            acc[mf] = __builtin_amdgcn_mfma_f32_16x16x32_f16(a0, bfrag[0], acc[mf], 0, 0, 0);
            acc[mf] = __builtin_amdgcn_mfma_f32_16x16x32_f16(a1, bfrag[1], acc[mf], 0, 0, 0);
        }
        __builtin_amdgcn_s_setprio(0);

        // LDS-visibility barrier ONLY: in-flight gathers ride across.
        lds_barrier();
    }

    // ---- epilogue: D[px][f], col = lane&15 -> f, row = (lane>>4)*4 + reg -> px ----
    float* orow = out + ((size_t)((m * 128 + h) * 128 + pxg)) * 128;
    const int f = n0 + r;
#pragma unroll
    for (int mf = 0; mf < 4; ++mf) {
        int px0e = mf * 16 + g * 4;
#pragma unroll
        for (int qq = 0; qq < 4; ++qq)
            orow[(size_t)(px0e + qq) * 128 + f] = acc[mf][qq];
    }
}

// ---------------- fp32 fallback (if ws too small) ----------------

constexpr int Hh   = 128;
constexpr int Wdim = 128;
constexpr int Cc   = 64;
constexpr int NTAP = 9;
constexpr int Ff   = 128;
constexpr int PXB  = 128;
constexpr int SPAD = 132;

__global__ __launch_bounds__(256, 2)
void defconv_f32(const float* __restrict__ x,
                 const float* __restrict__ offs,
                 const float* __restrict__ Wt,
                 float* __restrict__ out)
{
    __shared__ float s_tile[Cc][SPAD];
    __shared__ float w_tile[Cc][Ff];
    __shared__ float off_lds[PXB * 2 * NTAP];

    const int t   = threadIdx.x;
    const int bid = blockIdx.x;
    const int m   = bid >> 7;
    const int h   = bid & 127;

    const float* offrow = offs + (size_t)(m * Hh + h) * Wdim * (2 * NTAP);
    for (int i = t; i < PXB * 2 * NTAP; i += 256) off_lds[i] = offrow[i];

    const int pg = t & 15;
    const int fg = t >> 4;
    const int p0 = pg * 8;
    const int f0 = fg * 8;

    float acc[8][8];
#pragma unroll
    for (int a = 0; a < 8; ++a)
#pragma unroll
        for (int b = 0; b < 8; ++b) acc[a][b] = 0.f;

    const float* xbase = x + (size_t)m * Hh * Wdim * Cc;
    __syncthreads();

    for (int n = 0; n < NTAP; ++n) {
#pragma unroll
        for (int i = 0; i < 8; ++i) {
            int idx = t + 256 * i;
            int c   = idx >> 5;
            int f4  = (idx & 31) * 4;
            *(float4*)&w_tile[c][f4] =
                *(const float4*)(Wt + ((size_t)c * NTAP + n) * Ff + f4);
        }
#pragma unroll
        for (int i = 0; i < 8; ++i) {
            int task = t + 256 * i;
            int px   = task >> 4;
            int c4   = (task & 15) * 4;
            float o0 = off_lds[px * (2 * NTAP) + 2 * n];
            float o1 = off_lds[px * (2 * NTAP) + 2 * n + 1];
            float ci = fminf(fmaxf((float)h  + o0, 0.f), 127.f);
            float cj = fminf(fmaxf((float)px + o1, 0.f), 127.f);
            int i0 = (int)floorf(ci);
            int i1 = (int)ceilf(ci);
            int j0 = (int)floorf(cj);
            int j1 = (int)ceilf(cj);
            float fi = ci - (float)i0;
            float fj = cj - (float)j0;
            const float* r00 = xbase + ((size_t)i0 * Wdim + j0) * Cc + c4;
            const float* r01 = xbase + ((size_t)i0 * Wdim + j1) * Cc + c4;
            const float* r10 = xbase + ((size_t)i1 * Wdim + j0) * Cc + c4;
            const float* r11 = xbase + ((size_t)i1 * Wdim + j1) * Cc + c4;
            float4 vlt = *(const float4*)r00;
            float4 vrt = *(const float4*)r01;
            float4 vlb = *(const float4*)r10;
            float4 vrb = *(const float4*)r11;
            {
                float vt = vlt.x + (vrt.x - vlt.x) * fj;
                float vb = vlb.x + (vrb.x - vlb.x) * fj;
                s_tile[c4 + 0][px] = vt + (vb - vt) * fi;
            }
            {
                float vt = vlt.y + (vrt.y - vlt.y) * fj;
                float vb = vlb.y + (vrb.y - vlb.y) * fj;
                s_tile[c4 + 1][px] = vt + (vb - vt) * fi;
            }
            {
                float vt = vlt.z + (vrt.z - vlt.z) * fj;
                float vb = vlb.z + (vrb.z - vlb.z) * fj;
                s_tile[c4 + 2][px] = vt + (vb - vt) * fi;
            }
            {
                float vt = vlt.w + (vrt.w - vlt.w) * fj;
                float vb = vlb.w + (vrb.w - vlb.w) * fj;
                s_tile[c4 + 3][px] = vt + (vb - vt) * fi;
            }
        }
        __syncthreads();
        for (int c = 0; c < Cc; ++c) {
            float a[8], b[8];
            *(float4*)&a[0] = *(const float4*)&s_tile[c][p0];
            *(float4*)&a[4] = *(const float4*)&s_tile[c][p0 + 4];
            *(float4*)&b[0] = *(const float4*)&w_tile[c][f0];
            *(float4*)&b[4] = *(const float4*)&w_tile[c][f0 + 4];
#pragma unroll
            for (int pp = 0; pp < 8; ++pp)
#pragma unroll
                for (int ff = 0; ff < 8; ++ff)
                    acc[pp][ff] = fmaf(a[pp], b[ff], acc[pp][ff]);
        }
        __syncthreads();
    }

    float* orow = out + (size_t)(m * Hh + h) * Wdim * Ff;
#pragma unroll
    for (int pp = 0; pp < 8; ++pp) {
        float4 v0 = make_float4(acc[pp][0], acc[pp][1], acc[pp][2], acc[pp][3]);
        float4 v1 = make_float4(acc[pp][4], acc[pp][5], acc[pp][6], acc[pp][7]);
        *(float4*)&orow[(size_t)(p0 + pp) * Ff + f0]     = v0;
        *(float4*)&orow[(size_t)(p0 + pp) * Ff + f0 + 4] = v1;
    }
}

// ---------------- launch ----------------

extern "C" void kernel_launch(void* const* d_in, const int* in_sizes, int n_in,
                              void* d_out, int out_size, void* d_ws, size_t ws_size,
                              hipStream_t stream) {
    const float* x    = (const float*)d_in[0];
    const float* offs = (const float*)d_in[1];
    const float* W    = (const float*)d_in[2];
    float* out        = (float*)d_out;

    const size_t XH_BYTES = (size_t)8 * 128 * 128 * 64 * 2;   // 16,777,216
    const size_t WT_BYTES = (size_t)9 * 8 * 2 * 64 * 8 * 2;   // 147,456

    if (ws_size >= XH_BYTES + WT_BYTES) {
        __half* xh = (__half*)d_ws;
        __half* wt = (__half*)((char*)d_ws + XH_BYTES);
        cvt_w_kernel<<<dim3(288),  dim3(256), 0, stream>>>(W, wt);
        cvt_x_kernel<<<dim3(4096), dim3(256), 0, stream>>>(x, xh);
        defconv_mfma<<<dim3(2048), dim3(512), 0, stream>>>(offs, xh, wt, out);
    } else {
        defconv_f32<<<dim3(1024), dim3(256), 0, stream>>>(x, offs, W, out);
    }
}

// Round 20
// 53.041 us; speedup vs baseline: 1.2165x; 1.1214x over previous
//
#include <hip/hip_runtime.h>
#include <hip/hip_fp16.h>
#include <cstddef>

// Deformable conv: x(8,128,128,64) f32, offsets(8,128,128,18) f32, W(64,9,128) f32
// out(8,128,128,128) f32.
//
// Round 20: R16 main kernel verbatim (best: 44.5us) + fused single prepass
// kernel (x->f16 and W->fragment-ordered f16 in one dispatch; saves a launch).
//   Session conclusions baked in: N-split 4-wave 64px blocks are traffic-
//   optimal (A x4 via LDS + B x1 via L1 < any M-split); occupancy/TLP levers
//   null (R17/R19); barrier-drain null (R16); per-tap offset reloads cost 2x
//   (R8); launch_bounds must leave >=64 VGPR or cross-iter Gathers spill (R10).

typedef __attribute__((ext_vector_type(8))) _Float16 f16x8;
typedef __attribute__((ext_vector_type(4))) float    f32x4;

struct __align__(16) H2x4 { __half2 a, b, c, d; };

// ---------------- fused prepass: blocks [0,4096) convert x, [4096,4384) W ----

__global__ void cvt_fused_kernel(const float* __restrict__ x, __half* __restrict__ xh,
                                 const float* __restrict__ W, __half* __restrict__ wt2) {
    int bid = blockIdx.x;
    if (bid < 4096) {
        int i = bid * 256 + threadIdx.x;           // 1,048,576 threads * 8 elems
        const float4* p = (const float4*)x + (size_t)i * 2;
        float4 a = p[0], b = p[1];
        H2x4 o;
        o.a = __floats2half2_rn(a.x, a.y);
        o.b = __floats2half2_rn(a.z, a.w);
        o.c = __floats2half2_rn(b.x, b.y);
        o.d = __floats2half2_rn(b.z, b.w);
        ((H2x4*)xh)[i] = o;
    } else {
        // Fragment-ordered W: wt2[(((n*4 + wv)*4 + (nf*2+kf))*64 + ln)*8 + e]
        //   = W[c][n][f], c = kf*32 + (ln>>4)*8 + e, f = wv*32 + nf*16 + (ln&15).
        int idx = (bid - 4096) * 256 + threadIdx.x;   // 73728 = 288*256 exactly
        int e  = idx & 7;
        int ln = (idx >> 3) & 63;
        int fr = (idx >> 9) & 3;
        int wv = (idx >> 11) & 3;
        int n  = idx >> 13;
        int nf = fr >> 1, kf = fr & 1;
        int r = ln & 15, g = ln >> 4;
        int c = kf * 32 + g * 8 + e;
        int f = wv * 32 + nf * 16 + r;
        wt2[idx] = __float2half_rn(W[((size_t)c * 9 + n) * 128 + f]);
    }
}

// ---------------- main MFMA kernel (R16 verbatim) ----------------

// sampled tile: [64 px][64 ch] f16, 128 B/row, XOR-swizzled 16B slots:
//   byte(px, slot) = px*128 + ((slot*16) ^ ((px&7)<<4))
// (write: task(px,c8) -> slot c8; read: ch-octet s at slot s^(px&7)).
// Verified: 0 bank conflicts, correct output (R8..R19).

struct Gather {
    H2x4 v00, v01, v10, v11;
    __half2 wA, wB;      // {w00,w01}, {w10,w11}
};

__device__ inline void issue_gather(const char* __restrict__ ximg,
                                    const unsigned short* __restrict__ pb,
                                    const __half2 (*__restrict__ pw)[2],
                                    int px, int c8, Gather& G)
{
    int base = pb[px];
    G.wA = pw[px][0];
    G.wB = pw[px][1];
    int i0 = base >> 7, j0 = base & 127;
    size_t b00 = ((size_t)base << 7) + (c8 << 4);   // bytes; 128 B per pixel
    int di = (i0 < 127) ? (128 * 128) : 0;
    int dj = (j0 < 127) ? 128 : 0;
    G.v00 = *(const H2x4*)(ximg + b00);
    G.v01 = *(const H2x4*)(ximg + b00 + dj);
    G.v10 = *(const H2x4*)(ximg + b00 + di);
    G.v11 = *(const H2x4*)(ximg + b00 + di + dj);
}

__device__ inline void blend_store(char* __restrict__ buf, unsigned byteoff, const Gather& G)
{
    __half2 w00 = __low2half2(G.wA), w01 = __high2half2(G.wA);
    __half2 w10 = __low2half2(G.wB), w11 = __high2half2(G.wB);
    H2x4 r;
    r.a = __hfma2(G.v11.a, w11, __hfma2(G.v10.a, w10, __hfma2(G.v01.a, w01, __hmul2(G.v00.a, w00))));
    r.b = __hfma2(G.v11.b, w11, __hfma2(G.v10.b, w10, __hfma2(G.v01.b, w01, __hmul2(G.v00.b, w00))));
    r.c = __hfma2(G.v11.c, w11, __hfma2(G.v10.c, w10, __hfma2(G.v01.c, w01, __hmul2(G.v00.c, w00))));
    r.d = __hfma2(G.v11.d, w11, __hfma2(G.v10.d, w10, __hfma2(G.v01.d, w01, __hmul2(G.v00.d, w00))));
    *(H2x4*)(buf + byteoff) = r;
}

// barrier that does NOT drain vmcnt: LDS-write visibility only (R16-verified).
__device__ inline void lds_barrier() {
    __builtin_amdgcn_sched_barrier(0);
    asm volatile("s_waitcnt lgkmcnt(0)" ::: "memory");
    __builtin_amdgcn_s_barrier();
    __builtin_amdgcn_sched_barrier(0);
}

__global__ __launch_bounds__(256, 4)
void defconv_mfma(const float* __restrict__ offs,
                  const __half* __restrict__ xh,
                  const __half* __restrict__ wt,
                  float* __restrict__ out)
{
    __shared__ char sbuf[2][64 * 128];             // 16 KB, double-buffered
    __shared__ unsigned short p_base[9][64];       // (i0<<7)|j0
    __shared__ __half2 p_w[9][64][2];              // bilinear corner weights

    const int t = threadIdx.x;

    // XCD swizzle: dispatch i -> XCD i%8 (heuristic); give XCD k image k.
    int bid = blockIdx.x;
    int wid = (bid & 7) * 256 + (bid >> 3);        // bijective, 2048 % 8 == 0
    const int m   = wid >> 8;                      // image == XCD
    const int h   = (wid >> 1) & 127;              // row
    const int q   = wid & 1;                       // px half
    const int pxg = q * 64;

    // ---- phase 0: bilinear params per (px, tap) -> LDS (read offsets ONCE) ----
    const float* offrow = offs + ((size_t)((m * 128 + h) * 128 + pxg)) * 18;
    for (int i = t; i < 576; i += 256) {
        int px = i & 63, n = i >> 6;
        float o0 = offrow[px * 18 + 2 * n];
        float o1 = offrow[px * 18 + 2 * n + 1];
        float ci = fminf(fmaxf((float)h + o0, 0.f), 127.f);
        float cj = fminf(fmaxf((float)(pxg + px) + o1, 0.f), 127.f);
        int i0 = (int)ci;   // floor, ci >= 0
        int j0 = (int)cj;
        float fi = ci - (float)i0, fj = cj - (float)j0;
        float gi = 1.f - fi,       gj = 1.f - fj;
        p_base[n][px] = (unsigned short)((i0 << 7) | j0);
        p_w[n][px][0] = __floats2half2_rn(gi * gj, gi * fj);
        p_w[n][px][1] = __floats2half2_rn(fi * gj, fi * fj);
    }

    const char* ximg = (const char*)(xh + (size_t)m * (128 * 128 * 64));
    const int ln = t & 63;
    const int wv = t >> 6;
    const int r  = ln & 15;
    const int g  = ln >> 4;
    const int n0 = wv * 32;                        // wave's filter strip
    const unsigned rmask = (unsigned)((r & 7) << 4);

    // task split: T0 -> px0 = t>>3 (0..31), T1 -> px0+32 (32..63); c8 = t&7
    const int px0 = t >> 3;
    const int c8  = t & 7;
    const unsigned off0 = (unsigned)(px0 * 128 + ((c8 * 16) ^ ((px0 & 7) << 4)));
    const unsigned off1 = off0 + 32 * 128;

    f32x4 acc[4][2] = {};

    __syncthreads();   // params ready (full drain, once)

    Gather G0, G1;

    // ---- prologue: stage tap 0 fully; prefetch tap 1 into regs ----
    issue_gather(ximg, p_base[0], p_w[0], px0,      c8, G0);
    issue_gather(ximg, p_base[0], p_w[0], px0 + 32, c8, G1);
    blend_store(sbuf[0], off0, G0);
    blend_store(sbuf[0], off1, G1);
    issue_gather(ximg, p_base[1], p_w[1], px0,      c8, G0);
    issue_gather(ximg, p_base[1], p_w[1], px0 + 32, c8, G1);
    lds_barrier();

#pragma unroll 2
    for (int n = 0; n < 9; ++n) {
        char* cur = sbuf[n & 1];
        char* nxt = sbuf[(n + 1) & 1];

        // B fragments for tap n — fragment-ordered, fully coalesced 1KB/instr
        f16x8 bfrag[2][2];
        const __half* wb = wt + (size_t)(n * 4 + wv) * (4 * 512);
#pragma unroll
        for (int nf = 0; nf < 2; ++nf)
#pragma unroll
            for (int kf = 0; kf < 2; ++kf)
                bfrag[nf][kf] = *(const f16x8*)(wb + ((nf * 2 + kf) * 64 + ln) * 8);

        // blend tap n+1 (loads issued a FULL iteration ago), refill with tap n+2
        if (n < 8) blend_store(nxt, off0, G0);
        if (n < 7) issue_gather(ximg, p_base[n + 2], p_w[n + 2], px0, c8, G0);

        __builtin_amdgcn_s_setprio(1);
#pragma unroll
        for (int mf = 0; mf < 2; ++mf) {
            int row = mf * 16 + r;
            unsigned o0 = (unsigned)(row * 128) + ((unsigned)(g * 16)      ^ rmask);
            unsigned o1 = (unsigned)(row * 128) + ((unsigned)(g * 16 + 64) ^ rmask);
            f16x8 a0 = *(const f16x8*)(cur + o0);
            f16x8 a1 = *(const f16x8*)(cur + o1);
            acc[mf][0] = __builtin_amdgcn_mfma_f32_16x16x32_f16(a0, bfrag[0][0], acc[mf][0], 0, 0, 0);
            acc[mf][1] = __builtin_amdgcn_mfma_f32_16x16x32_f16(a0, bfrag[1][0], acc[mf][1], 0, 0, 0);
            acc[mf][0] = __builtin_amdgcn_mfma_f32_16x16x32_f16(a1, bfrag[0][1], acc[mf][0], 0, 0, 0);
            acc[mf][1] = __builtin_amdgcn_mfma_f32_16x16x32_f16(a1, bfrag[1][1], acc[mf][1], 0, 0, 0);
        }
        __builtin_amdgcn_s_setprio(0);

        if (n < 8) blend_store(nxt, off1, G1);
        if (n < 7) issue_gather(ximg, p_base[n + 2], p_w[n + 2], px0 + 32, c8, G1);

        __builtin_amdgcn_s_setprio(1);
#pragma unroll
        for (int mf = 2; mf < 4; ++mf) {
            int row = mf * 16 + r;
            unsigned o0 = (unsigned)(row * 128) + ((unsigned)(g * 16)      ^ rmask);
            unsigned o1 = (unsigned)(row * 128) + ((unsigned)(g * 16 + 64) ^ rmask);
            f16x8 a0 = *(const f16x8*)(cur + o0);
            f16x8 a1 = *(const f16x8*)(cur + o1);
            acc[mf][0] = __builtin_amdgcn_mfma_f32_16x16x32_f16(a0, bfrag[0][0], acc[mf][0], 0, 0, 0);
            acc[mf][1] = __builtin_amdgcn_mfma_f32_16x16x32_f16(a0, bfrag[1][0], acc[mf][1], 0, 0, 0);
            acc[mf][0] = __builtin_amdgcn_mfma_f32_16x16x32_f16(a1, bfrag[0][1], acc[mf][0], 0, 0, 0);
            acc[mf][1] = __builtin_amdgcn_mfma_f32_16x16x32_f16(a1, bfrag[1][1], acc[mf][1], 0, 0, 0);
        }
        __builtin_amdgcn_s_setprio(0);

        // LDS-visibility barrier ONLY: in-flight gathers ride across.
        lds_barrier();
    }

    // ---- epilogue: D[px][f], col = lane&15 -> f, row = (lane>>4)*4 + reg -> px ----
    float* orow = out + ((size_t)((m * 128 + h) * 128 + pxg)) * 128;
#pragma unroll
    for (int mf = 0; mf < 4; ++mf)
#pragma unroll
        for (int nf = 0; nf < 2; ++nf) {
            int f    = n0 + nf * 16 + r;
            int px0e = mf * 16 + g * 4;
#pragma unroll
            for (int qq = 0; qq < 4; ++qq)
                orow[(size_t)(px0e + qq) * 128 + f] = acc[mf][nf][qq];
        }
}

// ---------------- fp32 fallback (if ws too small) ----------------

constexpr int Hh   = 128;
constexpr int Wdim = 128;
constexpr int Cc   = 64;
constexpr int NTAP = 9;
constexpr int Ff   = 128;
constexpr int PXB  = 128;
constexpr int SPAD = 132;

__global__ __launch_bounds__(256, 2)
void defconv_f32(const float* __restrict__ x,
                 const float* __restrict__ offs,
                 const float* __restrict__ Wt,
                 float* __restrict__ out)
{
    __shared__ float s_tile[Cc][SPAD];
    __shared__ float w_tile[Cc][Ff];
    __shared__ float off_lds[PXB * 2 * NTAP];

    const int t   = threadIdx.x;
    const int bid = blockIdx.x;
    const int m   = bid >> 7;
    const int h   = bid & 127;

    const float* offrow = offs + (size_t)(m * Hh + h) * Wdim * (2 * NTAP);
    for (int i = t; i < PXB * 2 * NTAP; i += 256) off_lds[i] = offrow[i];

    const int pg = t & 15;
    const int fg = t >> 4;
    const int p0 = pg * 8;
    const int f0 = fg * 8;

    float acc[8][8];
#pragma unroll
    for (int a = 0; a < 8; ++a)
#pragma unroll
        for (int b = 0; b < 8; ++b) acc[a][b] = 0.f;

    const float* xbase = x + (size_t)m * Hh * Wdim * Cc;
    __syncthreads();

    for (int n = 0; n < NTAP; ++n) {
#pragma unroll
        for (int i = 0; i < 8; ++i) {
            int idx = t + 256 * i;
            int c   = idx >> 5;
            int f4  = (idx & 31) * 4;
            *(float4*)&w_tile[c][f4] =
                *(const float4*)(Wt + ((size_t)c * NTAP + n) * Ff + f4);
        }
#pragma unroll
        for (int i = 0; i < 8; ++i) {
            int task = t + 256 * i;
            int px   = task >> 4;
            int c4   = (task & 15) * 4;
            float o0 = off_lds[px * (2 * NTAP) + 2 * n];
            float o1 = off_lds[px * (2 * NTAP) + 2 * n + 1];
            float ci = fminf(fmaxf((float)h  + o0, 0.f), 127.f);
            float cj = fminf(fmaxf((float)px + o1, 0.f), 127.f);
            int i0 = (int)floorf(ci);
            int i1 = (int)ceilf(ci);
            int j0 = (int)floorf(cj);
            int j1 = (int)ceilf(cj);
            float fi = ci - (float)i0;
            float fj = cj - (float)j0;
            const float* r00 = xbase + ((size_t)i0 * Wdim + j0) * Cc + c4;
            const float* r01 = xbase + ((size_t)i0 * Wdim + j1) * Cc + c4;
            const float* r10 = xbase + ((size_t)i1 * Wdim + j0) * Cc + c4;
            const float* r11 = xbase + ((size_t)i1 * Wdim + j1) * Cc + c4;
            float4 vlt = *(const float4*)r00;
            float4 vrt = *(const float4*)r01;
            float4 vlb = *(const float4*)r10;
            float4 vrb = *(const float4*)r11;
            {
                float vt = vlt.x + (vrt.x - vlt.x) * fj;
                float vb = vlb.x + (vrb.x - vlb.x) * fj;
                s_tile[c4 + 0][px] = vt + (vb - vt) * fi;
            }
            {
                float vt = vlt.y + (vrt.y - vlt.y) * fj;
                float vb = vlb.y + (vrb.y - vlb.y) * fj;
                s_tile[c4 + 1][px] = vt + (vb - vt) * fi;
            }
            {
                float vt = vlt.z + (vrt.z - vlt.z) * fj;
                float vb = vlb.z + (vrb.z - vlb.z) * fj;
                s_tile[c4 + 2][px] = vt + (vb - vt) * fi;
            }
            {
                float vt = vlt.w + (vrt.w - vlt.w) * fj;
                float vb = vlb.w + (vrb.w - vlb.w) * fj;
                s_tile[c4 + 3][px] = vt + (vb - vt) * fi;
            }
        }
        __syncthreads();
        for (int c = 0; c < Cc; ++c) {
            float a[8], b[8];
            *(float4*)&a[0] = *(const float4*)&s_tile[c][p0];
            *(float4*)&a[4] = *(const float4*)&s_tile[c][p0 + 4];
            *(float4*)&b[0] = *(const float4*)&w_tile[c][f0];
            *(float4*)&b[4] = *(const float4*)&w_tile[c][f0 + 4];
#pragma unroll
            for (int pp = 0; pp < 8; ++pp)
#pragma unroll
                for (int ff = 0; ff < 8; ++ff)
                    acc[pp][ff] = fmaf(a[pp], b[ff], acc[pp][ff]);
        }
        __syncthreads();
    }

    float* orow = out + (size_t)(m * Hh + h) * Wdim * Ff;
#pragma unroll
    for (int pp = 0; pp < 8; ++pp) {
        float4 v0 = make_float4(acc[pp][0], acc[pp][1], acc[pp][2], acc[pp][3]);
        float4 v1 = make_float4(acc[pp][4], acc[pp][5], acc[pp][6], acc[pp][7]);
        *(float4*)&orow[(size_t)(p0 + pp) * Ff + f0]     = v0;
        *(float4*)&orow[(size_t)(p0 + pp) * Ff + f0 + 4] = v1;
    }
}

// ---------------- launch ----------------

extern "C" void kernel_launch(void* const* d_in, const int* in_sizes, int n_in,
                              void* d_out, int out_size, void* d_ws, size_t ws_size,
                              hipStream_t stream) {
    const float* x    = (const float*)d_in[0];
    const float* offs = (const float*)d_in[1];
    const float* W    = (const float*)d_in[2];
    float* out        = (float*)d_out;

    const size_t XH_BYTES = (size_t)8 * 128 * 128 * 64 * 2;   // 16,777,216
    const size_t WT_BYTES = (size_t)9 * 4 * 4 * 64 * 8 * 2;   // 147,456

    if (ws_size >= XH_BYTES + WT_BYTES) {
        __half* xh = (__half*)d_ws;
        __half* wt = (__half*)((char*)d_ws + XH_BYTES);
        cvt_fused_kernel<<<dim3(4384), dim3(256), 0, stream>>>(x, xh, W, wt);
        defconv_mfma<<<dim3(2048), dim3(256), 0, stream>>>(offs, xh, wt, out);
    } else {
        defconv_f32<<<dim3(1024), dim3(256), 0, stream>>>(x, offs, W, out);
    }
}